// Round 10
// baseline (110.627 us; speedup 1.0000x reference)
//
#include <hip/hip_runtime.h>
#include <cstdint>
#include <cstddef>

#define B_ 4
#define L_ 4096
#define E_ 1024
#define H_ 16
#define D_ 64
#define BH_ 64
#define ST2_ 4160        // 4096 kv + 64 ksum (fp32 partials)

typedef __attribute__((ext_vector_type(8))) short short8v;
typedef __attribute__((ext_vector_type(4))) float f32x4;

__device__ __forceinline__ float sigk(float x) {
    // sigmoid(0.6053*x - 4.102) = 1/(1+exp(4.102 - 0.6053*x))
    return __builtin_amdgcn_rcpf(1.0f + __expf(4.102f - 0.6053f * x));
}
// fp32 -> bf16 (RNE) and back, bit ops only
__device__ __forceinline__ unsigned short bfh(float f) {
    union { float f; unsigned u; } v; v.f = f;
    const unsigned r = v.u + 0x7fffu + ((v.u >> 16) & 1u);
    return (unsigned short)(r >> 16);
}
__device__ __forceinline__ float bf2f(unsigned short s) {
    union { unsigned u; float f; } v; v.u = ((unsigned)s) << 16;
    return v.f;
}

// MFMA 16x16x32_bf16 layouts (HW-verified, learn_hip m89/m156/m162):
//   A: lane l holds A[m=l&15][k=4*(l>>4)+(j&3)+16*(j>>2)], j=0..7
//   B: lane l holds B[k(same)][n=l&15]
//   C: lane l, reg r holds C[row=4*(l>>4)+r][col=l&15]

// ---------------- Kernel 1: partial kv[d][e] per (b,h,chunk) ----------------
// V hi/lo converted ONCE per tile (1 fragment slot per thread) into
// double-buffered LDS. Wave w owns d-slice [16w,16w+16). ksum accumulates
// the SAME rounded phi values as the MFMA (num/den weight consistency).
// Grid = BH_*nch blocks; nch=32 -> 8 blocks/CU (round-9 was grid-capped at 4).
__global__ void __launch_bounds__(256) kv_partial_kernel(
    const float* __restrict__ K, const float* __restrict__ V,
    float* __restrict__ partial, int nch, int rowsPerCh, int nt)
{
    __shared__ short8v Bfrag[2 * 8 * 64];   // [buf][t*2+hl][lane], 16 KB

    const int ch = blockIdx.x % nch;
    const int bh = blockIdx.x / nch;
    const int b = bh >> 4, h = bh & 15;
    const int tid = threadIdx.x;
    const int w = tid >> 6, l = tid & 63;
    const int g = l >> 4, m = l & 15;
    const int k4 = g << 2;
    const int col = (w << 4) + m;   // V-stage column (t=w) == A d-column

    const float* Kp = K + (size_t)(b * L_ + ch * rowsPerCh) * E_ + h * D_ + col;
    const float* Vp = V + (size_t)(b * L_ + ch * rowsPerCh) * E_ + h * D_ + col;

    f32x4 acc[4];
    #pragma unroll
    for (int t = 0; t < 4; ++t) acc[t] = (f32x4){0.f, 0.f, 0.f, 0.f};
    float ksacc = 0.f;

    float vr[8], kr[8];
    #pragma unroll
    for (int j = 0; j < 8; ++j) {
        const int ko = k4 + (j & 3) + ((j >> 2) << 4);
        vr[j] = Vp[(size_t)ko * E_];
        kr[j] = Kp[(size_t)ko * E_];
    }
    {   // stage tile 0 (this thread's slot: t=w, lane l)
        short8v Bh, Bl;
        #pragma unroll
        for (int j = 0; j < 8; ++j) {
            const unsigned short hb = bfh(vr[j]);
            Bh[j] = (short)hb;
            Bl[j] = (short)bfh(vr[j] - bf2f(hb));
        }
        Bfrag[(w << 1) * 64 + l]       = Bh;
        Bfrag[((w << 1) + 1) * 64 + l] = Bl;
    }
    __syncthreads();

    #pragma unroll 2
    for (int t = 0; t < nt; ++t) {
        const int buf = (t & 1) << 9;
        float vr2[8], kr2[8];
        if (t + 1 < nt) {   // issue next tile's loads; land during MFMA
            #pragma unroll
            for (int j = 0; j < 8; ++j) {
                const int ko = ((t + 1) << 5) + k4 + (j & 3) + ((j >> 2) << 4);
                vr2[j] = Vp[(size_t)ko * E_];
                kr2[j] = Kp[(size_t)ko * E_];
            }
        }
        short8v Ah;
        #pragma unroll
        for (int j = 0; j < 8; ++j) {
            const unsigned short hb = bfh(sigk(kr[j]));
            Ah[j] = (short)hb;
            ksacc += bf2f(hb);          // exact same weights as the MFMA
        }
        #pragma unroll
        for (int tt = 0; tt < 4; ++tt) {
            const short8v Bh = Bfrag[buf + (tt << 1) * 64 + l];
            const short8v Bl = Bfrag[buf + ((tt << 1) + 1) * 64 + l];
            acc[tt] = __builtin_amdgcn_mfma_f32_16x16x32_bf16(Ah, Bh, acc[tt], 0, 0, 0);
            acc[tt] = __builtin_amdgcn_mfma_f32_16x16x32_bf16(Ah, Bl, acc[tt], 0, 0, 0);
        }
        if (t + 1 < nt) {   // convert + stage next tile into other buffer
            const int nbuf = ((t + 1) & 1) << 9;
            short8v Bh, Bl;
            #pragma unroll
            for (int j = 0; j < 8; ++j) {
                const unsigned short hb = bfh(vr2[j]);
                Bh[j] = (short)hb;
                Bl[j] = (short)bfh(vr2[j] - bf2f(hb));
            }
            Bfrag[nbuf + (w << 1) * 64 + l]       = Bh;
            Bfrag[nbuf + ((w << 1) + 1) * 64 + l] = Bl;
            #pragma unroll
            for (int j = 0; j < 8; ++j) kr[j] = kr2[j];
        }
        __syncthreads();
    }

    // ksum[d]: combine the 4 lane-groups (same m, different k coverage)
    ksacc += __shfl_xor(ksacc, 16);
    ksacc += __shfl_xor(ksacc, 32);

    const size_t pbase = ((size_t)ch * BH_ + bh) * ST2_;
    #pragma unroll
    for (int tt = 0; tt < 4; ++tt)
        #pragma unroll
        for (int r = 0; r < 4; ++r)
            partial[pbase + (size_t)((w << 4) + k4 + r) * 64 + (tt << 4) + m]
                = acc[tt][r];
    if (g == 0) partial[pbase + 4096 + (w << 4) + m] = ksacc;
}

// ---- Kernel 2: reduce partials -> FRAGMENT-ORDERED packed bf16 hi|lo kv ----
// kv2 layout: u32[sp(8)][lane(64)][jj(8)] per bh, sp = (d>>5)*4 + (e>>4).
// K3 then stages with a straight coalesced copy (no permute, no scatter).
__global__ void __launch_bounds__(256) kv_reduce_kernel(
    const float* __restrict__ partial, unsigned* __restrict__ kv2,
    float* __restrict__ ksumf, int nch)
{
    const int bh = blockIdx.x >> 2, part = blockIdx.x & 3;
    const int tid = threadIdx.x;
    #pragma unroll
    for (int i = 0; i < 4; ++i) {
        const int idx = (part << 10) + (i << 8) + tid;   // (d<<6)|e
        float s = 0.f;
        for (int c = 0; c < nch; ++c)
            s += partial[((size_t)c * BH_ + bh) * ST2_ + idx];
        const unsigned short hb = bfh(s);
        const unsigned short lb = bfh(s - bf2f(hb));
        const unsigned u = ((unsigned)hb << 16) | (unsigned)lb;
        const int d = idx >> 6, e = idx & 63;
        const int kk = d & 31;
        const int gg = (kk & 15) >> 2;
        const int jj = (kk & 3) + ((kk >> 4) << 2);
        const int lane = (e & 15) + (gg << 4);
        const int sp = ((d >> 5) << 2) + (e >> 4);
        kv2[(size_t)bh * 4096 + ((sp << 6) + lane) * 8 + jj] = u;
    }
    if (part == 0 && tid < 64) {
        float s = 0.f;
        for (int c = 0; c < nch; ++c)
            s += partial[((size_t)c * BH_ + bh) * ST2_ + 4096 + tid];
        ksumf[bh * 64 + tid] = s;
    }
}

// ---------------- Kernel 3: out = (phiQ @ kv) / (phiQ @ ksum) ----------------
// 64 q-rows per block (grid 4096). kvfrag staging = pure coalesced copy.
// phiQ converted hi/lo AT STAGE TIME, stored packed-u32 in A-fragment layout
// [qq(4)][w(4)][lane(64)] (lane-stride 16B -> conflict-free b128 reads,
// all compile-time register indices). den uses bf2f(hi)+bf2f(lo) == exact
// MFMA weights. LDS 32 KB, no pads, one sync.
__global__ void __launch_bounds__(256) attn_out_kernel(
    const float* __restrict__ Q, const unsigned* __restrict__ kv2,
    const float* __restrict__ ksumf, float* __restrict__ out)
{
    __shared__ unsigned kvf[4096];   // fragment-ordered kv (16 KB)
    __shared__ uint4 QA4[1024];      // [qq(4)][w(4)][lane(64)] (16 KB)

    const int bh = blockIdx.x >> 6, qb = blockIdx.x & 63;
    const int b = bh >> 4, h = bh & 15;
    const int tid = threadIdx.x;
    const int w = tid >> 6, l = tid & 63;
    const int g = l >> 4, m = l & 15;
    const int k4 = g << 2;
    const int rowb0 = qb << 6;

    // stage kv fragments: straight copy, coalesced, conflict-free
    #pragma unroll
    for (int i = 0; i < 16; ++i)
        kvf[tid + (i << 8)] = kv2[(size_t)bh * 4096 + tid + (i << 8)];

    // stage phi(Q) hi|lo in fragment layout (each element converted once)
    #pragma unroll
    for (int i = 0; i < 4; ++i) {
        const int idx = tid + (i << 8);
        const int r = idx >> 4;              // row in tile; r>>4 == i
        const int c4i = (idx & 15) << 2;
        const float4 qv = *(const float4*)(
            Q + (size_t)(b * L_ + rowb0 + r) * E_ + h * D_ + c4i);
        const float qa[4] = {qv.x, qv.y, qv.z, qv.w};
        unsigned u[4];
        #pragma unroll
        for (int j = 0; j < 4; ++j) {
            const float ph = sigk(qa[j]);
            const unsigned short hb = bfh(ph);
            const unsigned short lb = bfh(ph - bf2f(hb));
            u[j] = ((unsigned)hb << 16) | (unsigned)lb;
        }
        const int lane = (tid >> 4) + ((tid & 3) << 4);  // (r&15) + 16*((c4i>>2)&3)
        const int qq = (tid >> 2) & 3;                   // j-block (c4i-derived)
        QA4[(((qq << 2) + i) << 6) + lane] = make_uint4(u[0], u[1], u[2], u[3]);
    }

    float ksl[16];
    #pragma unroll
    for (int ji = 0; ji < 16; ++ji) {
        const int ks = ji >> 3, j = ji & 7;
        ksl[ji] = ksumf[bh * 64 + (ks << 5) + k4 + (j & 3) + ((j >> 2) << 4)];
    }
    __syncthreads();

    // A fragments + den (compile-time indices throughout)
    const uint4 aq0 = QA4[((0 << 2) + w) * 64 + l];
    const uint4 aq1 = QA4[((1 << 2) + w) * 64 + l];
    const uint4 aq2 = QA4[((2 << 2) + w) * 64 + l];
    const uint4 aq3 = QA4[((3 << 2) + w) * 64 + l];
    const unsigned au[16] = {aq0.x, aq0.y, aq0.z, aq0.w,
                             aq1.x, aq1.y, aq1.z, aq1.w,
                             aq2.x, aq2.y, aq2.z, aq2.w,
                             aq3.x, aq3.y, aq3.z, aq3.w};
    short8v Ah[2], Al[2];
    float den = 0.f;
    #pragma unroll
    for (int ji = 0; ji < 16; ++ji) {
        const unsigned uu = au[ji];
        const unsigned short hb = (unsigned short)(uu >> 16);
        const unsigned short lb = (unsigned short)(uu & 0xffffu);
        Ah[ji >> 3][ji & 7] = (short)hb;
        Al[ji >> 3][ji & 7] = (short)lb;
        den = fmaf(bf2f(hb) + bf2f(lb), ksl[ji], den);
    }

    f32x4 acc[4];
    #pragma unroll
    for (int tt = 0; tt < 4; ++tt) acc[tt] = (f32x4){0.f, 0.f, 0.f, 0.f};
    #pragma unroll
    for (int ks = 0; ks < 2; ++ks)
        #pragma unroll
        for (int tt = 0; tt < 4; ++tt) {
            const int base = ((((ks << 2) + tt) << 6) + l) << 3;
            const uint4 b0 = *(const uint4*)&kvf[base];
            const uint4 b1 = *(const uint4*)&kvf[base + 4];
            const unsigned bu[8] = {b0.x, b0.y, b0.z, b0.w,
                                    b1.x, b1.y, b1.z, b1.w};
            short8v Bh, Bl;
            #pragma unroll
            for (int j = 0; j < 8; ++j) {
                Bh[j] = (short)(bu[j] >> 16);
                Bl[j] = (short)(bu[j] & 0xffffu);
            }
            acc[tt] = __builtin_amdgcn_mfma_f32_16x16x32_bf16(Ah[ks], Bh, acc[tt], 0, 0, 0);
            acc[tt] = __builtin_amdgcn_mfma_f32_16x16x32_bf16(Ah[ks], Bl, acc[tt], 0, 0, 0);
            acc[tt] = __builtin_amdgcn_mfma_f32_16x16x32_bf16(Al[ks], Bh, acc[tt], 0, 0, 0);
        }

    den += __shfl_xor(den, 16);
    den += __shfl_xor(den, 32);
    float inv[4];
    #pragma unroll
    for (int r = 0; r < 4; ++r)
        inv[r] = __builtin_amdgcn_rcpf(__shfl(den, k4 + r));

    float* op = out + (size_t)(b * L_ + rowb0 + (w << 4)) * E_ + h * D_;
    #pragma unroll
    for (int tt = 0; tt < 4; ++tt)
        #pragma unroll
        for (int r = 0; r < 4; ++r)
            op[(size_t)(k4 + r) * E_ + (tt << 4) + m] = acc[tt][r] * inv[r];
}

extern "C" void kernel_launch(void* const* d_in, const int* in_sizes, int n_in,
                              void* d_out, int out_size, void* d_ws, size_t ws_size,
                              hipStream_t stream) {
    const float* Q = (const float*)d_in[0];
    const float* K = (const float*)d_in[1];
    const float* V = (const float*)d_in[2];
    float* out = (float*)d_out;

    int nch = 32;
    while (nch > 4 &&
           (size_t)nch * BH_ * ST2_ * 4 + (size_t)BH_ * 4096 * 4 + BH_ * 64 * 4
               > ws_size)
        nch >>= 1;
    const int rowsPerCh = L_ / nch;
    const int nt = rowsPerCh / 32;

    float* partial  = (float*)d_ws;                                   // nch*BH_*ST2_ f32
    unsigned* kv2   = (unsigned*)(partial + (size_t)nch * BH_ * ST2_); // BH_*4096 u32
    float* ksumf    = (float*)(kv2 + (size_t)BH_ * 4096);             // BH_*64 f32

    hipLaunchKernelGGL(kv_partial_kernel, dim3(BH_ * nch), dim3(256), 0, stream,
                       K, V, partial, nch, rowsPerCh, nt);
    hipLaunchKernelGGL(kv_reduce_kernel, dim3(BH_ * 4), dim3(256), 0, stream,
                       partial, kv2, ksumf, nch);
    hipLaunchKernelGGL(attn_out_kernel, dim3(BH_ * 64), dim3(256), 0, stream,
                       Q, kv2, ksumf, out);
}

// Round 11
// 67.419 us; speedup vs baseline: 1.6409x; 1.6409x over previous
//
#include <hip/hip_runtime.h>
#include <cstdint>
#include <cstddef>

#define B_ 4
#define L_ 4096
#define E_ 1024
#define H_ 16
#define D_ 64
#define BH_ 64
#define ST2_ 4160        // 4096 kv + 64 ksum (fp32 partials)
#define NCH_ 16
#define RPC_ (L_/NCH_)   // 256 k-rows per chunk
#define NT_ (RPC_/32)    // 8 tiles of 32 k-rows

typedef __attribute__((ext_vector_type(8))) short short8v;
typedef __attribute__((ext_vector_type(4))) float f32x4;

__device__ __forceinline__ float sigk(float x) {
    // sigmoid(0.6053*x - 4.102) = 1/(1+exp(4.102 - 0.6053*x))
    return __builtin_amdgcn_rcpf(1.0f + __expf(4.102f - 0.6053f * x));
}
// fp32 -> bf16 (RNE) and back, bit ops only
__device__ __forceinline__ unsigned short bfh(float f) {
    union { float f; unsigned u; } v; v.f = f;
    const unsigned r = v.u + 0x7fffu + ((v.u >> 16) & 1u);
    return (unsigned short)(r >> 16);
}
__device__ __forceinline__ float bf2f(unsigned short s) {
    union { unsigned u; float f; } v; v.u = ((unsigned)s) << 16;
    return v.f;
}

// MFMA 16x16x32_bf16 layouts (HW-verified, learn_hip m89/m156/m162):
//   A: lane l holds A[m=l&15][k=4*(l>>4)+(j&3)+16*(j>>2)], j=0..7
//   B: lane l holds B[k(same)][n=l&15]
//   C: lane l, reg r holds C[row=4*(l>>4)+r][col=l&15]

// ---------------- Kernel 1: partial kv[d][e] per (b,h,chunk) ----------------
// Depth-2 software pipeline: tile t+2's loads issue at iter t (ping-pong reg
// slots, unroll-2 keeps indices compile-time); sched_barrier(0) stops the
// scheduler from sinking the loads to their use (round-10's VGPR=40 proved it
// was doing exactly that, leaving per-tile latency unhidden).
__global__ void __launch_bounds__(256) kv_partial_kernel(
    const float* __restrict__ K, const float* __restrict__ V,
    float* __restrict__ partial)
{
    __shared__ short8v Bfrag[2 * 8 * 64];   // [buf][t*2+hl][lane], 16 KB

    const int ch = blockIdx.x & (NCH_ - 1);
    const int bh = blockIdx.x / NCH_;
    const int b = bh >> 4, h = bh & 15;
    const int tid = threadIdx.x;
    const int w = tid >> 6, l = tid & 63;
    const int g = l >> 4, m = l & 15;
    const int k4 = g << 2;
    const int col = (w << 4) + m;   // V-stage column (t=w) == A d-column

    const float* Kp = K + (size_t)(b * L_ + ch * RPC_) * E_ + h * D_ + col;
    const float* Vp = V + (size_t)(b * L_ + ch * RPC_) * E_ + h * D_ + col;

    f32x4 acc[4];
    #pragma unroll
    for (int t = 0; t < 4; ++t) acc[t] = (f32x4){0.f, 0.f, 0.f, 0.f};
    float ksacc = 0.f;

    float kr[2][8], vr[2][8];   // ping-pong prefetch slots
    // tile 0 -> slot 0
    #pragma unroll
    for (int j = 0; j < 8; ++j) {
        const int ko = k4 + (j & 3) + ((j >> 2) << 4);
        kr[0][j] = Kp[(size_t)ko * E_];
        vr[0][j] = Vp[(size_t)ko * E_];
    }
    {   // stage tile 0 into buf 0
        short8v Bh, Bl;
        #pragma unroll
        for (int j = 0; j < 8; ++j) {
            const unsigned short hb = bfh(vr[0][j]);
            Bh[j] = (short)hb;
            Bl[j] = (short)bfh(vr[0][j] - bf2f(hb));
        }
        Bfrag[(w << 1) * 64 + l]       = Bh;
        Bfrag[((w << 1) + 1) * 64 + l] = Bl;
    }
    // tile 1 -> slot 1
    #pragma unroll
    for (int j = 0; j < 8; ++j) {
        const int ko = 32 + k4 + (j & 3) + ((j >> 2) << 4);
        kr[1][j] = Kp[(size_t)ko * E_];
        vr[1][j] = Vp[(size_t)ko * E_];
    }
    __syncthreads();

    #pragma unroll 2
    for (int t = 0; t < NT_; ++t) {
        const int cur = t & 1, nxt = cur ^ 1;
        // 1. A fragment (phi of tile t's K); ksum gets the SAME rounded values
        short8v Ah;
        #pragma unroll
        for (int j = 0; j < 8; ++j) {
            const unsigned short hb = bfh(sigk(kr[cur][j]));
            Ah[j] = (short)hb;
            ksacc += bf2f(hb);
        }
        // 2. issue tile t+2 loads into slot cur (kr[cur] just consumed)
        if (t + 2 < NT_) {
            #pragma unroll
            for (int j = 0; j < 8; ++j) {
                const int ko = ((t + 2) << 5) + k4 + (j & 3) + ((j >> 2) << 4);
                kr[cur][j] = Kp[(size_t)ko * E_];
                vr[cur][j] = Vp[(size_t)ko * E_];
            }
        }
        __builtin_amdgcn_sched_barrier(0);   // loads must not sink below here
        // 3. MFMA on buf cur (staged at iter t-1)
        {
            const int buf = cur << 9;
            #pragma unroll
            for (int tt = 0; tt < 4; ++tt) {
                const short8v Bh = Bfrag[buf + (tt << 1) * 64 + l];
                const short8v Bl = Bfrag[buf + ((tt << 1) + 1) * 64 + l];
                acc[tt] = __builtin_amdgcn_mfma_f32_16x16x32_bf16(Ah, Bh, acc[tt], 0, 0, 0);
                acc[tt] = __builtin_amdgcn_mfma_f32_16x16x32_bf16(Ah, Bl, acc[tt], 0, 0, 0);
            }
        }
        // 4. stage tile t+1 (loaded >=1 full iteration ago) into buf nxt
        if (t + 1 < NT_) {
            const int nb = nxt << 9;
            short8v Bh, Bl;
            #pragma unroll
            for (int j = 0; j < 8; ++j) {
                const unsigned short hb = bfh(vr[nxt][j]);
                Bh[j] = (short)hb;
                Bl[j] = (short)bfh(vr[nxt][j] - bf2f(hb));
            }
            Bfrag[nb + (w << 1) * 64 + l]       = Bh;
            Bfrag[nb + ((w << 1) + 1) * 64 + l] = Bl;
        }
        __syncthreads();
    }

    // ksum[d]: combine the 4 lane-groups (same m, different k coverage)
    ksacc += __shfl_xor(ksacc, 16);
    ksacc += __shfl_xor(ksacc, 32);

    const size_t pbase = ((size_t)ch * BH_ + bh) * ST2_;
    #pragma unroll
    for (int tt = 0; tt < 4; ++tt)
        #pragma unroll
        for (int r = 0; r < 4; ++r)
            partial[pbase + (size_t)((w << 4) + k4 + r) * 64 + (tt << 4) + m]
                = acc[tt][r];
    if (g == 0) partial[pbase + 4096 + (w << 4) + m] = ksacc;
}

// ---- Kernel 2: reduce partials -> fragment-ordered kv2H / kv2L + ksum ----
// Each thread reduces an even/odd d-pair at one e: the pair lands in the SAME
// fragment u32 (jj even/odd <-> d even/odd), so hi and lo regions are packed
// u32 arrays that K3 copies straight.  Layout: u32[sp(8)][lane(64)][jq(4)].
__global__ void __launch_bounds__(256) kv_reduce_kernel(
    const float* __restrict__ partial, unsigned* __restrict__ kv2H,
    unsigned* __restrict__ kv2L, float* __restrict__ ksumf)
{
    const int bh = blockIdx.x >> 2, part = blockIdx.x & 3;
    const int tid = threadIdx.x;
    const int e = tid & 63;
    #pragma unroll
    for (int it = 0; it < 2; ++it) {
        const int pr = (tid >> 6) + (it << 2);       // 0..7 pair index
        const int d0 = (part << 4) + (pr << 1);      // even d
        float s0 = 0.f, s1 = 0.f;
        #pragma unroll
        for (int c = 0; c < NCH_; ++c) {
            const size_t pb = ((size_t)c * BH_ + bh) * ST2_;
            s0 += partial[pb + (d0 << 6) + e];
            s1 += partial[pb + ((d0 + 1) << 6) + e];
        }
        const unsigned short h0 = bfh(s0), h1 = bfh(s1);
        const unsigned short l0 = bfh(s0 - bf2f(h0));
        const unsigned short l1 = bfh(s1 - bf2f(h1));
        const int kk = d0 & 31;
        const int gg = (kk & 15) >> 2;
        const int jq = ((kk & 3) >> 1) + ((kk >> 4) << 1);   // jj>>1
        const int lane = (e & 15) + (gg << 4);
        const int sp = ((d0 >> 5) << 2) + (e >> 4);
        const size_t idx = (size_t)bh * 2048 + (((sp << 6) + lane) << 2) + jq;
        kv2H[idx] = (unsigned)h0 | ((unsigned)h1 << 16);
        kv2L[idx] = (unsigned)l0 | ((unsigned)l1 << 16);
    }
    if (part == 0 && tid < 64) {
        float s = 0.f;
        #pragma unroll
        for (int c = 0; c < NCH_; ++c)
            s += partial[((size_t)c * BH_ + bh) * ST2_ + 4096 + tid];
        ksumf[bh * 64 + tid] = s;
    }
}

// ---------------- Kernel 3: out = (phiQ @ kv) / (phiQ @ ksum) ----------------
// kvH/kvL staged by straight uint4 copy into short8v[slot][lane] (16B lane
// stride -> conflict-free b128 reads; round-10's packed-u32 layout was 32B
// stride = 16-way).  Qt: coalesced global float4 reads, 2-way-free LDS
// writes, 4-way (1.58x) scalar fragment gathers.
__global__ void __launch_bounds__(256) attn_out_kernel(
    const float* __restrict__ Q, const unsigned* __restrict__ kv2H,
    const unsigned* __restrict__ kv2L, const float* __restrict__ ksumf,
    float* __restrict__ out)
{
    __shared__ short8v kvH[8 * 64];   // 8 KB
    __shared__ short8v kvL[8 * 64];   // 8 KB
    __shared__ float Qt[64 * 65];     // 16.25 KB

    const int bh = blockIdx.x >> 6, qb = blockIdx.x & 63;
    const int b = bh >> 4, h = bh & 15;
    const int tid = threadIdx.x;
    const int w = tid >> 6, l = tid & 63;
    const int g = l >> 4, m = l & 15;
    const int k4 = g << 2;
    const int rowb0 = qb << 6;

    {   // stage kv fragments: straight copy, coalesced & conflict-free
        const uint4* srcH = (const uint4*)(kv2H + (size_t)bh * 2048);
        const uint4* srcL = (const uint4*)(kv2L + (size_t)bh * 2048);
        uint4* dH = (uint4*)kvH;
        uint4* dL = (uint4*)kvL;
        dH[tid]       = srcH[tid];
        dH[tid + 256] = srcH[tid + 256];
        dL[tid]       = srcL[tid];
        dL[tid + 256] = srcL[tid + 256];
    }
    // stage 64 Q rows (coalesced float4 reads; 2-way-free scalar LDS writes)
    #pragma unroll
    for (int i = 0; i < 4; ++i) {
        const int idx = tid + (i << 8);
        const int r = idx >> 4, c4i = (idx & 15) << 2;
        const float4 qv = *(const float4*)(
            Q + (size_t)(b * L_ + rowb0 + r) * E_ + h * D_ + c4i);
        float* qd = Qt + r * 65 + c4i;
        qd[0] = qv.x; qd[1] = qv.y; qd[2] = qv.z; qd[3] = qv.w;
    }
    float ksl[16];
    #pragma unroll
    for (int ji = 0; ji < 16; ++ji) {
        const int ks = ji >> 3, j = ji & 7;
        ksl[ji] = ksumf[bh * 64 + (ks << 5) + k4 + (j & 3) + ((j >> 2) << 4)];
    }
    __syncthreads();

    // A fragments (phiQ hi/lo) + den from the same rounded weights
    const int rl = (w << 4) + m;         // this lane's q-row (tile-local)
    short8v Ah[2], Al[2];
    float den = 0.f;
    #pragma unroll
    for (int ks = 0; ks < 2; ++ks)
        #pragma unroll
        for (int j = 0; j < 8; ++j) {
            const float qv =
                Qt[rl * 65 + (ks << 5) + k4 + (j & 3) + ((j >> 2) << 4)];
            const float ph = sigk(qv);
            const unsigned short hb = bfh(ph);
            const unsigned short lb = bfh(ph - bf2f(hb));
            Ah[ks][j] = (short)hb;
            Al[ks][j] = (short)lb;
            den = fmaf(bf2f(hb) + bf2f(lb), ksl[(ks << 3) + j], den);
        }

    f32x4 acc[4];
    #pragma unroll
    for (int tt = 0; tt < 4; ++tt) acc[tt] = (f32x4){0.f, 0.f, 0.f, 0.f};
    #pragma unroll
    for (int ks = 0; ks < 2; ++ks)
        #pragma unroll
        for (int tt = 0; tt < 4; ++tt) {
            const int slot = (ks << 2) + tt;
            const short8v Bh = kvH[slot * 64 + l];
            const short8v Bl = kvL[slot * 64 + l];
            acc[tt] = __builtin_amdgcn_mfma_f32_16x16x32_bf16(Ah[ks], Bh, acc[tt], 0, 0, 0);
            acc[tt] = __builtin_amdgcn_mfma_f32_16x16x32_bf16(Ah[ks], Bl, acc[tt], 0, 0, 0);
            acc[tt] = __builtin_amdgcn_mfma_f32_16x16x32_bf16(Al[ks], Bh, acc[tt], 0, 0, 0);
        }

    den += __shfl_xor(den, 16);
    den += __shfl_xor(den, 32);
    float inv[4];
    #pragma unroll
    for (int r = 0; r < 4; ++r)
        inv[r] = __builtin_amdgcn_rcpf(__shfl(den, k4 + r));

    float* op = out + (size_t)(b * L_ + rowb0 + (w << 4)) * E_ + h * D_;
    #pragma unroll
    for (int tt = 0; tt < 4; ++tt)
        #pragma unroll
        for (int r = 0; r < 4; ++r)
            op[(size_t)(k4 + r) * E_ + (tt << 4) + m] = acc[tt][r] * inv[r];
}

extern "C" void kernel_launch(void* const* d_in, const int* in_sizes, int n_in,
                              void* d_out, int out_size, void* d_ws, size_t ws_size,
                              hipStream_t stream) {
    const float* Q = (const float*)d_in[0];
    const float* K = (const float*)d_in[1];
    const float* V = (const float*)d_in[2];
    float* out = (float*)d_out;

    float* partial = (float*)d_ws;                                    // 16*64*4160 f32 (~17 MB)
    unsigned* kv2H = (unsigned*)(partial + (size_t)NCH_ * BH_ * ST2_); // 64*2048 u32 (512 KB)
    unsigned* kv2L = kv2H + (size_t)BH_ * 2048;                        // 512 KB
    float* ksumf   = (float*)(kv2L + (size_t)BH_ * 2048);              // 16 KB

    hipLaunchKernelGGL(kv_partial_kernel, dim3(BH_ * NCH_), dim3(256), 0, stream,
                       K, V, partial);
    hipLaunchKernelGGL(kv_reduce_kernel, dim3(BH_ * 4), dim3(256), 0, stream,
                       partial, kv2H, kv2L, ksumf);
    hipLaunchKernelGGL(attn_out_kernel, dim3(BH_ * 64), dim3(256), 0, stream,
                       Q, kv2H, kv2L, ksumf, out);
}